// Round 1
// baseline (818.424 us; speedup 1.0000x reference)
//
#include <hip/hip_runtime.h>

// rate_RNN_mante: T=1000 sequential scan, B=64, IN=4, H=512, OUT=3, P=2.
// Rank-2 recurrence: Wr @ r == (l*pin) @ (pout^T @ r)  -> two dot products.
// Mapping: 1 wave (64 lanes) per batch; each lane owns HPT=8 hidden units in
// registers; all weights register-resident; x staged in LDS; one fused
// 5-value __shfl_xor butterfly reduction per step (s0,s1 for next step,
// y0,y1,y2 output now). No __syncthreads in the hot loop.

#define T_STEPS 1000
#define BATCH   64
#define H       512
#define OUTDIM  3
#define HPT     8   // H / 64 lanes

__global__ __launch_bounds__(64, 1) void rnn_scan_kernel(
    const float* __restrict__ x,     // [T, B, 4, 1]
    const float* __restrict__ Win,   // [H, 4]
    const float* __restrict__ Wout,  // [3, H]
    const float* __restrict__ pin,   // [H, 2]
    const float* __restrict__ pout,  // [H, 2]
    const float* __restrict__ l,     // [2]
    float* __restrict__ out)         // [T, B, 3, 1]
{
    const int b    = blockIdx.x;
    const int lane = threadIdx.x;

    // Stage this batch's input sequence into LDS (16 KB): x4[t*B + b]
    __shared__ float4 xs[T_STEPS];
    const float4* x4 = (const float4*)x;
    for (int t = lane; t < T_STEPS; t += 64)
        xs[t] = x4[t * BATCH + b];

    // Per-lane weights, h = lane + 64*k
    float win0[HPT], win1[HPT], win2[HPT], win3[HPT];
    float a0[HPT], a1[HPT];          // l_p * pin[h,p]
    float po0[HPT], po1[HPT];        // pout[h,p]
    float wo0[HPT], wo1[HPT], wo2[HPT];
    const float l0 = l[0], l1 = l[1];
#pragma unroll
    for (int k = 0; k < HPT; ++k) {
        const int h = lane + 64 * k;
        float4 w = ((const float4*)Win)[h];
        win0[k] = w.x; win1[k] = w.y; win2[k] = w.z; win3[k] = w.w;
        float2 pi = ((const float2*)pin)[h];
        a0[k] = l0 * pi.x; a1[k] = l1 * pi.y;
        float2 po = ((const float2*)pout)[h];
        po0[k] = po.x; po1[k] = po.y;
        wo0[k] = Wout[0 * H + h];
        wo1[k] = Wout[1 * H + h];
        wo2[k] = Wout[2 * H + h];
    }

    const float lm = 0.9048374180359595f;  // float(exp(-0.1)) == float(exp(-DT/TAUM))
    const float om = 1.0f - lm;

    float mem[HPT];
#pragma unroll
    for (int k = 0; k < HPT; ++k) mem[k] = 0.0f;
    float s0 = 0.0f, s1 = 0.0f;  // pout^T tanh(mem), carried across steps; tanh(0)=0

    __syncthreads();  // one wave, but make LDS staging formally visible

    float* outp = out + b * OUTDIM;
    for (int t = 0; t < T_STEPS; ++t) {
        const float4 xt = xs[t];
        float p0 = 0.f, p1 = 0.f, p2 = 0.f, p3 = 0.f, p4 = 0.f;
#pragma unroll
        for (int k = 0; k < HPT; ++k) {
            float I = win0[k] * xt.x + win1[k] * xt.y
                    + win2[k] * xt.z + win3[k] * xt.w
                    + a0[k] * s0 + a1[k] * s1;
            float m = lm * mem[k] + om * I;
            mem[k] = m;
            // tanh(m) = 1 - 2/(exp(2m)+1); saturates correctly at +-1
            float e = __expf(2.0f * m);
            float r = 1.0f - 2.0f / (e + 1.0f);
            p0 += po0[k] * r;
            p1 += po1[k] * r;
            p2 += wo0[k] * r;
            p3 += wo1[k] * r;
            p4 += wo2[k] * r;
        }
        // Fused 5-value wave64 butterfly reduction (all lanes get the totals)
#pragma unroll
        for (int m = 1; m < 64; m <<= 1) {
            p0 += __shfl_xor(p0, m, 64);
            p1 += __shfl_xor(p1, m, 64);
            p2 += __shfl_xor(p2, m, 64);
            p3 += __shfl_xor(p3, m, 64);
            p4 += __shfl_xor(p4, m, 64);
        }
        s0 = p0; s1 = p1;  // feed next step's recurrent input
        if (lane == 0) {
            float* o = outp + (size_t)t * (BATCH * OUTDIM);
            o[0] = p2; o[1] = p3; o[2] = p4;
        }
    }
}

extern "C" void kernel_launch(void* const* d_in, const int* in_sizes, int n_in,
                              void* d_out, int out_size, void* d_ws, size_t ws_size,
                              hipStream_t stream) {
    const float* x    = (const float*)d_in[0];
    const float* Win  = (const float*)d_in[1];
    const float* Wout = (const float*)d_in[2];
    const float* pin  = (const float*)d_in[3];
    const float* pout = (const float*)d_in[4];
    const float* l    = (const float*)d_in[5];
    rnn_scan_kernel<<<BATCH, 64, 0, stream>>>(x, Win, Wout, pin, pout, l,
                                              (float*)d_out);
}

// Round 2
// 435.087 us; speedup vs baseline: 1.8811x; 1.8811x over previous
//
#include <hip/hip_runtime.h>

// rate_RNN_mante: T=1000 sequential scan, B=64, IN=4, H=512, OUT=3, P=2.
// Rank-2 recurrence: Wr @ r == (l*pin) @ (pout^T @ r)  -> two dot products.
// One wave per batch; lane owns 8 hidden units (4 float2 pairs) in registers.
// Per step: one fused 5-value DPP wave-sum (VALU-only, no LDS) — s0,s1 via
// readlane feed the next step; y stored straight from lane 63.
// M = 2*mem is tracked so tanh(mem) = 1 - 2*rcp(exp(M)+1) with exp via __expf
// and rcp via v_rcp_f32 (no slow full-precision divide).

#define T_STEPS 1000
#define BATCH   64
#define H       512
#define OUTDIM  3
#define HV      4   // 8 hidden units per lane = 4 float2 groups

typedef float v2f __attribute__((ext_vector_type(2)));

template<int CTRL, int RM>
__device__ __forceinline__ float dpp_add(float x) {
    int mv = __builtin_amdgcn_update_dpp(0, __builtin_bit_cast(int, x),
                                         CTRL, RM, 0xf, true);
    return x + __builtin_bit_cast(float, mv);
}

// Full wave64 sum; total lands in lane 63 (other lanes hold partials).
__device__ __forceinline__ float wave_sum63(float x) {
    x = dpp_add<0x111, 0xf>(x);  // row_shr:1
    x = dpp_add<0x112, 0xf>(x);  // row_shr:2
    x = dpp_add<0x114, 0xf>(x);  // row_shr:4
    x = dpp_add<0x118, 0xf>(x);  // row_shr:8
    x = dpp_add<0x142, 0xa>(x);  // row_bcast:15 -> rows 1,3
    x = dpp_add<0x143, 0xc>(x);  // row_bcast:31 -> rows 2,3
    return x;
}

__device__ __forceinline__ float bcast63(float x) {
    return __builtin_bit_cast(float,
        __builtin_amdgcn_readlane(__builtin_bit_cast(int, x), 63));
}

__global__ __launch_bounds__(64, 1) void rnn_scan_kernel(
    const float* __restrict__ x,     // [T, B, 4, 1]
    const float* __restrict__ Win,   // [H, 4]
    const float* __restrict__ Wout,  // [3, H]
    const float* __restrict__ pin,   // [H, 2]
    const float* __restrict__ pout,  // [H, 2]
    const float* __restrict__ l,     // [2]
    float* __restrict__ out)         // [T, B, 3, 1]
{
    const int b    = blockIdx.x;
    const int lane = threadIdx.x;

    // Stage this batch's input sequence into LDS (16 KB)
    __shared__ float4 xs[T_STEPS];
    const float4* x4 = (const float4*)x;
    for (int t = lane; t < T_STEPS; t += 64)
        xs[t] = x4[t * BATCH + b];

    const float lm = 0.9048374180359595f;   // fp32(exp(-DT/TAUM)) = fp32(exp(-0.1))
    const float c  = 2.0f * (1.0f - lm);    // scale folded into input weights (M = 2*mem)
    const float l0 = l[0], l1 = l[1];

    // Per-lane weights; float2 group g, component j <-> h = lane + 64*(2g+j)
    v2f wx[HV], wy[HV], wz[HV], ww[HV];   // c * Win[h, 0..3]
    v2f a0[HV], a1[HV];                   // c * l_p * pin[h,p]
    v2f po0[HV], po1[HV];                 // pout[h,p]
    v2f wo0[HV], wo1[HV], wo2[HV];        // Wout[o,h]
    v2f M[HV];                            // 2 * mem
#pragma unroll
    for (int g = 0; g < HV; ++g) {
#pragma unroll
        for (int j = 0; j < 2; ++j) {
            const int h = lane + 64 * (2 * g + j);
            float4 w = ((const float4*)Win)[h];
            wx[g][j] = c * w.x; wy[g][j] = c * w.y;
            wz[g][j] = c * w.z; ww[g][j] = c * w.w;
            float2 pi = ((const float2*)pin)[h];
            a0[g][j] = c * l0 * pi.x; a1[g][j] = c * l1 * pi.y;
            float2 po = ((const float2*)pout)[h];
            po0[g][j] = po.x; po1[g][j] = po.y;
            wo0[g][j] = Wout[0 * H + h];
            wo1[g][j] = Wout[1 * H + h];
            wo2[g][j] = Wout[2 * H + h];
            M[g][j] = 0.0f;
        }
    }

    float s0 = 0.0f, s1 = 0.0f;   // pout^T tanh(mem); tanh(0) = 0
    __syncthreads();

    float* outp = out + b * OUTDIM;
#pragma unroll 2
    for (int t = 0; t < T_STEPS; ++t) {
        const float4 xt = xs[t];
        v2f acc0 = {0.f, 0.f}, acc1 = {0.f, 0.f}, acc2 = {0.f, 0.f},
            acc3 = {0.f, 0.f}, acc4 = {0.f, 0.f};
#pragma unroll
        for (int g = 0; g < HV; ++g) {
            // base (s-independent) can overlap previous step's reduction
            v2f base = wx[g] * xt.x + wy[g] * xt.y + wz[g] * xt.z + ww[g] * xt.w;
            v2f m = base + a0[g] * s0 + a1[g] * s1 + M[g] * lm;  // M' = lm*M + 2*om*I
            M[g] = m;
            // tanh(mem) = 1 - 2/(exp(2*mem)+1), exp via v_exp, rcp via v_rcp
            float e0 = __expf(m.x);
            float e1 = __expf(m.y);
            v2f r;
            r.x = fmaf(-2.0f, __builtin_amdgcn_rcpf(e0 + 1.0f), 1.0f);
            r.y = fmaf(-2.0f, __builtin_amdgcn_rcpf(e1 + 1.0f), 1.0f);
            acc0 += po0[g] * r;
            acc1 += po1[g] * r;
            acc2 += wo0[g] * r;
            acc3 += wo1[g] * r;
            acc4 += wo2[g] * r;
        }
        float p0 = acc0.x + acc0.y;
        float p1 = acc1.x + acc1.y;
        float p2 = acc2.x + acc2.y;
        float p3 = acc3.x + acc3.y;
        float p4 = acc4.x + acc4.y;
        // VALU-only wave reductions (independent chains, scheduler interleaves)
        p0 = wave_sum63(p0);
        p1 = wave_sum63(p1);
        p2 = wave_sum63(p2);
        p3 = wave_sum63(p3);
        p4 = wave_sum63(p4);
        s0 = bcast63(p0);             // SGPR broadcast for next step
        s1 = bcast63(p1);
        if (lane == 63) {             // y output straight from the reduced lane
            float* o = outp + (size_t)t * (BATCH * OUTDIM);
            o[0] = p2; o[1] = p3; o[2] = p4;
        }
    }
}

extern "C" void kernel_launch(void* const* d_in, const int* in_sizes, int n_in,
                              void* d_out, int out_size, void* d_ws, size_t ws_size,
                              hipStream_t stream) {
    const float* x    = (const float*)d_in[0];
    const float* Win  = (const float*)d_in[1];
    const float* Wout = (const float*)d_in[2];
    const float* pin  = (const float*)d_in[3];
    const float* pout = (const float*)d_in[4];
    const float* l    = (const float*)d_in[5];
    rnn_scan_kernel<<<BATCH, 64, 0, stream>>>(x, Win, Wout, pin, pout, l,
                                              (float*)d_out);
}

// Round 7
// 408.388 us; speedup vs baseline: 2.0040x; 1.0654x over previous
//
#include <hip/hip_runtime.h>

// rate_RNN_mante: T=1000 sequential scan, B=64, IN=4, H=512, OUT=3, P=2.
// Rank-2 recurrence: Wr @ r == (l*pin) @ (pout^T @ r)  -> two dot products.
// One wave per batch; lane owns 8 hidden units as 4 named v2f pairs (NO
// arrays -> force VGPR allocation). M~ = 2*log2e*mem is tracked so
// tanh(mem) = 1 - 2*rcp(exp2(M~)+1) uses native v_exp_f32 directly.
// Per step: prefetched x, s-independent prework, then a short s-dependent
// chain into one fused 5-value DPP wave-sum (VALU-only). y stored from lane 63.

#define T_STEPS 1000
#define BATCH   64
#define H       512
#define OUTDIM  3

typedef float v2f __attribute__((ext_vector_type(2)));

#if __has_builtin(__builtin_amdgcn_exp2f)
#define EXP2(x) __builtin_amdgcn_exp2f(x)
#else
#define EXP2(x) exp2f(x)
#endif

template<int CTRL, int RM>
__device__ __forceinline__ float dpp_add(float x) {
    int mv = __builtin_amdgcn_update_dpp(0, __builtin_bit_cast(int, x),
                                         CTRL, RM, 0xf, true);
    return x + __builtin_bit_cast(float, mv);
}

__device__ __forceinline__ float bcast63(float x) {
    return __builtin_bit_cast(float,
        __builtin_amdgcn_readlane(__builtin_bit_cast(int, x), 63));
}

__global__ __launch_bounds__(64, 1) void rnn_scan_kernel(
    const float* __restrict__ x,     // [T, B, 4, 1]
    const float* __restrict__ Win,   // [H, 4]
    const float* __restrict__ Wout,  // [3, H]
    const float* __restrict__ pin,   // [H, 2]
    const float* __restrict__ pout,  // [H, 2]
    const float* __restrict__ l,     // [2]
    float* __restrict__ out)         // [T, B, 3, 1]
{
    const int b    = blockIdx.x;
    const int lane = threadIdx.x;

    __shared__ float4 xs[T_STEPS];
    const float4* x4 = (const float4*)x;
    for (int t = lane; t < T_STEPS; t += 64)
        xs[t] = x4[t * BATCH + b];

    const float lm = 0.9048374180359595f;            // fp32(exp(-DT/TAUM))
    const float ct = 2.0f * 1.4426950408889634f * (1.0f - lm); // fold 2*log2e*(1-lm)
    const float l0 = l[0], l1 = l[1];

    // Named per-lane state: group G covers h = lane+64*(2G) and h = lane+64*(2G+1)
#define DECLG(G) v2f wx##G, wy##G, wz##G, ww##G, A0##G, A1##G, \
                     P0##G, P1##G, O0##G, O1##G, O2##G, MM##G;
    DECLG(0) DECLG(1) DECLG(2) DECLG(3)

#define LOADG(G, K0) do {                                                     \
    const int h0 = lane + 64 * (K0);                                          \
    const int h1 = h0 + 64;                                                   \
    float4 w0 = ((const float4*)Win)[h0];                                     \
    float4 w1 = ((const float4*)Win)[h1];                                     \
    wx##G = (v2f){ct * w0.x, ct * w1.x};                                      \
    wy##G = (v2f){ct * w0.y, ct * w1.y};                                      \
    wz##G = (v2f){ct * w0.z, ct * w1.z};                                      \
    ww##G = (v2f){ct * w0.w, ct * w1.w};                                      \
    float2 pi0 = ((const float2*)pin)[h0];                                    \
    float2 pi1 = ((const float2*)pin)[h1];                                    \
    A0##G = (v2f){ct * l0 * pi0.x, ct * l0 * pi1.x};                          \
    A1##G = (v2f){ct * l1 * pi0.y, ct * l1 * pi1.y};                          \
    float2 q0 = ((const float2*)pout)[h0];                                    \
    float2 q1 = ((const float2*)pout)[h1];                                    \
    P0##G = (v2f){q0.x, q1.x};                                                \
    P1##G = (v2f){q0.y, q1.y};                                                \
    O0##G = (v2f){Wout[0 * H + h0], Wout[0 * H + h1]};                        \
    O1##G = (v2f){Wout[1 * H + h0], Wout[1 * H + h1]};                        \
    O2##G = (v2f){Wout[2 * H + h0], Wout[2 * H + h1]};                        \
    MM##G = (v2f){0.0f, 0.0f};                                                \
} while (0)
    LOADG(0, 0); LOADG(1, 2); LOADG(2, 4); LOADG(3, 6);

    float s0 = 0.0f, s1 = 0.0f;   // pout^T tanh(mem); tanh(0) = 0
    __syncthreads();

    float* outp = out + b * OUTDIM;
    float4 xt = xs[0];
    for (int t = 0; t < T_STEPS; ++t) {
        // prefetch next step's input (latency hides under this step's chain)
        float4 xn = xs[(t + 1 < T_STEPS) ? t + 1 : 0];

        // s-independent prework: pre = lm*M + ct*(Win . x)
#define PREW(G) v2f pre##G = MM##G * lm + wx##G * xt.x + wy##G * xt.y          \
                           + wz##G * xt.z + ww##G * xt.w;
        PREW(0) PREW(1) PREW(2) PREW(3)

        // s-dependent: M' = pre + A1*s1 + A0*s0 ; r = tanh(mem')
#define STEPG(G)                                                              \
        MM##G = pre##G + A1##G * s1 + A0##G * s0;                             \
        v2f r##G;                                                             \
        {                                                                     \
            float e0 = EXP2(MM##G.x);                                         \
            float e1 = EXP2(MM##G.y);                                         \
            r##G.x = fmaf(-2.0f, __builtin_amdgcn_rcpf(e0 + 1.0f), 1.0f);     \
            r##G.y = fmaf(-2.0f, __builtin_amdgcn_rcpf(e1 + 1.0f), 1.0f);     \
        }
        STEPG(0) STEPG(1) STEPG(2) STEPG(3)

        // depth-2 tree accumulation, 5 outputs
#define ACC(NAME, W)                                                          \
        float NAME;                                                           \
        {                                                                     \
            v2f ua = W##0 * r0 + W##1 * r1;                                   \
            v2f ub = W##2 * r2 + W##3 * r3;                                   \
            v2f uc = ua + ub;                                                 \
            NAME = uc.x + uc.y;                                               \
        }
        ACC(p0, P0) ACC(p1, P1) ACC(p2, O0) ACC(p3, O1) ACC(p4, O2)

        // fused 5-value DPP wave-sum, chains hand-interleaved; total in lane 63
#define RND(CTRL, RM)                                                         \
        p0 = dpp_add<CTRL, RM>(p0); p1 = dpp_add<CTRL, RM>(p1);               \
        p2 = dpp_add<CTRL, RM>(p2); p3 = dpp_add<CTRL, RM>(p3);               \
        p4 = dpp_add<CTRL, RM>(p4);
        RND(0x111, 0xf)   // row_shr:1
        RND(0x112, 0xf)   // row_shr:2
        RND(0x114, 0xf)   // row_shr:4
        RND(0x118, 0xf)   // row_shr:8
        RND(0x142, 0xa)   // row_bcast:15 -> rows 1,3
        RND(0x143, 0xc)   // row_bcast:31 -> rows 2,3

        s0 = bcast63(p0);
        s1 = bcast63(p1);
        if (lane == 63) {
            float* o = outp + (size_t)t * (BATCH * OUTDIM);
            o[0] = p2; o[1] = p3; o[2] = p4;
        }
        xt = xn;
    }
}

extern "C" void kernel_launch(void* const* d_in, const int* in_sizes, int n_in,
                              void* d_out, int out_size, void* d_ws, size_t ws_size,
                              hipStream_t stream) {
    const float* x    = (const float*)d_in[0];
    const float* Win  = (const float*)d_in[1];
    const float* Wout = (const float*)d_in[2];
    const float* pin  = (const float*)d_in[3];
    const float* pout = (const float*)d_in[4];
    const float* l    = (const float*)d_in[5];
    rnn_scan_kernel<<<BATCH, 64, 0, stream>>>(x, Win, Wout, pin, pout, l,
                                              (float*)d_out);
}